// Round 3
// baseline (1114.114 us; speedup 1.0000x reference)
//
#include <hip/hip_runtime.h>

// HQQLinear: out[b,s,o] = sum_i x[b,s,i] * W[o,i] + bias[o]
// R4: 256x256 GEMM, 8 single-barrier windows/iter, (m-half x k-slice) clusters.
//   - Reads rebalanced to [8,8,4,4] b128/wave/window (was [12,4,8,0]): DS-pipe
//     time per window (<=64 b128/CU ~640cyc) now fits the 621cyc MFMA window.
//   - ONE barrier per window (8/iter, was 16): stage issued inside the window,
//     WAR-safe by construction (see schedule proof below).
//   - vmcnt drains at end-W3/end-W7 target a load issued ~2.3 windows earlier
//     (~1400cyc > 900cyc HBM latency) -> expected zero stall.
//   - Running stage pointers (+=BK, LDS buf toggle) cut per-stage VALU.
//   - Keeps: chunk swizzle phys=c^(r&7) (0 bank conflicts), bijective XCD
//     swizzle (1376=8*172), setprio around MFMA, sched_barrier(0) per cluster.
//
// Dims: M=8192, N=11008, K=4096. 32x43 tiles, 64 K-tiles, 32 iterations.

#define K_DIM 4096
#define N_DIM 11008
#define M_DIM 8192
#define NG 704512  // N_GROUPS = 4096*11008/64

#define BM 256
#define BN 256
#define BK 64
#define NIT 32  // (K_DIM/BK)/2 double-tile iterations

typedef __bf16 bf16;
typedef bf16 bf16x4 __attribute__((ext_vector_type(4)));
typedef bf16 bf16x8 __attribute__((ext_vector_type(8)));
typedef float f32x4 __attribute__((ext_vector_type(4)));

__device__ __forceinline__ void async_copy16(const void* g, void* l) {
  __builtin_amdgcn_global_load_lds(
      (const __attribute__((address_space(1))) void*)g,
      (__attribute__((address_space(3))) void*)l,
      16, 0, 0);
}

__device__ __forceinline__ void barrier_() {
  asm volatile("" ::: "memory");
  __builtin_amdgcn_s_barrier();
  asm volatile("" ::: "memory");
}
#define VMW(n) asm volatile("s_waitcnt vmcnt(" #n ")" ::: "memory")

// ---------------- x: fp32 -> bf16, 8 elems/thread ----------------
__global__ void cvt_x(const float* __restrict__ X, bf16* __restrict__ Xb) {
  const int idx = (blockIdx.x * 256 + threadIdx.x) * 8;
  const float4 v0 = *(const float4*)(X + idx);
  const float4 v1 = *(const float4*)(X + idx + 4);
  bf16x8 o;
  o[0] = (bf16)v0.x; o[1] = (bf16)v0.y; o[2] = (bf16)v0.z; o[3] = (bf16)v0.w;
  o[4] = (bf16)v1.x; o[5] = (bf16)v1.y; o[6] = (bf16)v1.z; o[7] = (bf16)v1.w;
  *(bf16x8*)(Xb + idx) = o;
}

// ---------------- W dequant: HQQ 4-bit -> bf16 [N][K], 8 groups/thread ------
__global__ void dequant_w(const int* __restrict__ Wq, const float* __restrict__ scale,
                          const float* __restrict__ zero, bf16* __restrict__ Wb) {
  const int idx = blockIdx.x * 256 + threadIdx.x;  // 32 * NG/8 threads
  const int r = idx / (NG / 8);                    // 0..31
  const int g = (idx - r * (NG / 8)) * 8;
  const int4 q0 = *(const int4*)(Wq + (size_t)r * NG + g);
  const int4 q1 = *(const int4*)(Wq + (size_t)r * NG + g + 4);
  const float4 sc0 = *(const float4*)(scale + g);
  const float4 sc1 = *(const float4*)(scale + g + 4);
  const float4 zp0 = *(const float4*)(zero + g);
  const float4 zp1 = *(const float4*)(zero + g + 4);
  const int c = g >> 12;    // g / 4096
  const int i = g & 4095;
  bf16x8 hi, lo;
  hi[0] = (bf16)(((float)((q0.x >> 4) & 0xF) - zp0.x) * sc0.x);
  hi[1] = (bf16)(((float)((q0.y >> 4) & 0xF) - zp0.y) * sc0.y);
  hi[2] = (bf16)(((float)((q0.z >> 4) & 0xF) - zp0.z) * sc0.z);
  hi[3] = (bf16)(((float)((q0.w >> 4) & 0xF) - zp0.w) * sc0.w);
  hi[4] = (bf16)(((float)((q1.x >> 4) & 0xF) - zp1.x) * sc1.x);
  hi[5] = (bf16)(((float)((q1.y >> 4) & 0xF) - zp1.y) * sc1.y);
  hi[6] = (bf16)(((float)((q1.z >> 4) & 0xF) - zp1.z) * sc1.z);
  hi[7] = (bf16)(((float)((q1.w >> 4) & 0xF) - zp1.w) * sc1.w);
  lo[0] = (bf16)(((float)(q0.x & 0xF) - zp0.x) * sc0.x);
  lo[1] = (bf16)(((float)(q0.y & 0xF) - zp0.y) * sc0.y);
  lo[2] = (bf16)(((float)(q0.z & 0xF) - zp0.z) * sc0.z);
  lo[3] = (bf16)(((float)(q0.w & 0xF) - zp0.w) * sc0.w);
  lo[4] = (bf16)(((float)(q1.x & 0xF) - zp1.x) * sc1.x);
  lo[5] = (bf16)(((float)(q1.y & 0xF) - zp1.y) * sc1.y);
  lo[6] = (bf16)(((float)(q1.z & 0xF) - zp1.z) * sc1.z);
  lo[7] = (bf16)(((float)(q1.w & 0xF) - zp1.w) * sc1.w);
  *(bf16x8*)(Wb + (size_t)(r * 172 + c) * 4096 + i) = hi;
  *(bf16x8*)(Wb + (size_t)((r + 32) * 172 + c) * 4096 + i) = lo;
}

// ---------------- GEMM: C[M][N] = A[M][K] * B[N][K]^T + bias ----------------
// LDS map (bytes): A half (b,h) at (b*2+h)*16384; B at 65536 + same.
// Row r at r*128; 16B chunk c at phys chunk c ^ (r&7).
//
// Iteration = 2 K-tiles: T0 (buf0) clusters C1-C4 in windows W1-W4,
// T1 (buf1) clusters C5-C8 in W5-W8. Cluster (mh,ks) = 16 MFMA (4m x 4n x 1ks).
// Window Wk = [BAR; reads for W(k+1)'s cluster; stage; mmq(Ck); (vmcnt)].
// Reads/wave: W8p:8 W1:8 W2:4 W3:4 W4:8 W5:8 W6:4 W7:4  (max 64 b128/CU).
// Stages: W1: T1.A(u0,u1) | W4: T2.B(u2,u3) | W5: T2.A | W8: T3.B.
// WAR (strict: stage into R only after barrier following R-reads' retirement):
//   buf1-A last read-issue W7p, consumed W8p, retired x-wave at end-W8p -> W1 OK
//   buf0-B last read-issue W1 (bQ), consumed W3, retired end-W3 -> W4 OK
//   buf0-A last read-issue W3, consumed W4, retired end-W4 -> W5 OK
//   buf1-B last read-issue W5 (bQ), consumed W7, retired end-W7 -> W8 OK
// Same-window stage/read regions disjoint in all 4 cases (checked per window).
// RAW: VMW(0) end-W3 drains T1 (last unit issued W1, 2.3 windows earlier);
//      VMW(0) end-W7 drains T2 (last unit issued W5). Queue is empty of
//      younger loads at both points, so the drain waits only on old loads.
__global__ __launch_bounds__(512, 2)
void gemm_bt(const bf16* __restrict__ A, const bf16* __restrict__ B,
             const float* __restrict__ bias, float* __restrict__ C) {
  extern __shared__ char smem[];

  const int tid = threadIdx.x;
  const int wave = tid >> 6;
  const int lane = tid & 63;
  const int l15 = lane & 15;
  const int quad = lane >> 4;
  const int wm = wave >> 2;  // 0..1 -> A half (128 output rows)
  const int wn = wave & 3;   // 0..3 -> 64 output cols

  // bijective XCD swizzle (1376 = 8*172), m-fastest within an XCD chunk.
  const int id = blockIdx.x;
  const int wg = (id & 7) * 172 + (id >> 3);
  const int bm = (wg & 31) * BM;
  const int bn = (wg >> 5) * BN;

  // ---- staging: thread covers row srow, phys chunk tid&7 ----
  const int srow = tid >> 3;
  const int qc = (tid & 7) ^ (srow & 7);        // inverse-swizzled logical chunk
  const int ldsWave = wave << 10;               // HW adds lane*16

  // running pointers: one per unit (u0=A-h0, u1=A-h1, u2=B-h0, u3=B-h1);
  // each stage call advances +BK and toggles the LDS dbuf bit.
  const bf16* pA0 = A + (size_t)(bm + srow) * K_DIM + qc * 8;
  const bf16* pA1 = pA0 + (size_t)128 * K_DIM;
  const bf16* pB0 = B + (size_t)(bn + srow) * K_DIM + qc * 8;
  const bf16* pB1 = pB0 + (size_t)128 * K_DIM;
  char* lA0 = smem + 0 + ldsWave;
  char* lA1 = smem + 16384 + ldsWave;
  char* lB0 = smem + 65536 + ldsWave;
  char* lB1 = smem + 65536 + 16384 + ldsWave;

  auto stage = [&](const bf16*& gp, char*& lp) {
    async_copy16(gp, lp);
    async_copy16(gp + (size_t)64 * K_DIM, lp + 8192);
    gp += BK;
    lp = (char*)((unsigned long long)lp ^ 32768ull);
  };

  // ---- fragment read offsets ----
  const int sw = l15 & 7;
  const int ro = l15 * 128;
  const int k0 = (quad ^ sw) << 4;          // ks=0 chunk byte offset
  const int k1 = ((quad + 4) ^ sw) << 4;    // ks=1
  const char* rdA0 = smem + wm * 16384 + ro;
  const char* rdB0 = smem + 65536 + (wn >> 1) * 16384 + (wn & 1) * 8192 + ro;
  const char* rdA1 = rdA0 + 32768;
  const char* rdB1 = rdB0 + 32768;

  auto ldA4 = [&](bf16x8 (&d)[4], const char* base, int fm, int kb) {
#pragma unroll
    for (int m = 0; m < 4; ++m)
      d[m] = *(const bf16x8*)(base + (fm + m) * 2048 + kb);
  };
  auto ldB4 = [&](bf16x8 (&d)[4], const char* base, int kb) {
#pragma unroll
    for (int n = 0; n < 4; ++n)
      d[n] = *(const bf16x8*)(base + n * 2048 + kb);
  };

  f32x4 acc[8][4];
#pragma unroll
  for (int m = 0; m < 8; ++m)
#pragma unroll
    for (int n = 0; n < 4; ++n) {
      f32x4 z = {0.f, 0.f, 0.f, 0.f};
      acc[m][n] = z;
    }

  // cluster: 16 independent MFMAs (no chains), one k-slice.
  auto mmq = [&](bf16x8 (&a)[4], bf16x8 (&b)[4], int mh) {
    __builtin_amdgcn_s_setprio(1);
#pragma unroll
    for (int m = 0; m < 4; ++m)
#pragma unroll
      for (int n = 0; n < 4; ++n)
        acc[mh + m][n] = __builtin_amdgcn_mfma_f32_16x16x32_bf16(
            a[m], b[n], acc[mh + m][n], 0, 0, 0);
    __builtin_amdgcn_s_setprio(0);
    __builtin_amdgcn_sched_barrier(0);
  };

  bf16x8 aA[4], aB[4], bP[4], bQ[4];

  // ---- prologue: T0 all units -> buf0; T1.B -> buf1 (in flight) ----
  stage(pA0, lA0); stage(pA1, lA1); stage(pB0, lB0); stage(pB1, lB1);  // T0
  stage(pB0, lB0); stage(pB1, lB1);                                    // T1.u2,u3
  VMW(4);  // T0 landed; T1.B in flight
  barrier_();
  ldA4(aA, rdA0, 0, k0); ldB4(bP, rdB0, k0);  // W0 reads -> C1

  for (int it = 0; it < NIT - 1; ++it) {
    // W1: C1=(T0,mh0,k0)
    barrier_();
    ldA4(aB, rdA0, 4, k0); ldB4(bQ, rdB0, k1);
    stage(pA0, lA0); stage(pA1, lA1);           // T1.u0,u1 -> buf1-A
    mmq(aA, bP, 0);
    // W2: C2=(T0,mh1,k0)
    barrier_();
    ldA4(aA, rdA0, 0, k1);
    mmq(aB, bP, 4);
    // W3: C3=(T0,mh0,k1)
    barrier_();
    ldA4(aB, rdA0, 4, k1);
    mmq(aA, bQ, 0);
    VMW(0);  // T1 fully landed (last unit issued W1, ~2.3 windows ago)
    // W4: C4=(T0,mh1,k1)
    barrier_();
    ldA4(aA, rdA1, 0, k0); ldB4(bP, rdB1, k0);
    stage(pB0, lB0); stage(pB1, lB1);           // T2.u2,u3 -> buf0-B
    mmq(aB, bQ, 4);
    // W5: C5=(T1,mh0,k0)
    barrier_();
    ldA4(aB, rdA1, 4, k0); ldB4(bQ, rdB1, k1);
    stage(pA0, lA0); stage(pA1, lA1);           // T2.u0,u1 -> buf0-A
    mmq(aA, bP, 0);
    // W6: C6=(T1,mh1,k0)
    barrier_();
    ldA4(aA, rdA1, 0, k1);
    mmq(aB, bP, 4);
    // W7: C7=(T1,mh0,k1)
    barrier_();
    ldA4(aB, rdA1, 4, k1);
    mmq(aA, bQ, 0);
    VMW(0);  // T2 fully landed (last unit issued W5)
    // W8: C8=(T1,mh1,k1)
    barrier_();
    ldA4(aA, rdA0, 0, k0); ldB4(bP, rdB0, k0);  // T2.C1 fragments
    stage(pB0, lB0); stage(pB1, lB1);           // T3.u2,u3 -> buf1-B
    mmq(aB, bQ, 4);
  }

  // ---- peeled last iteration (no T2/T3 stages, no W8 reads) ----
  barrier_();
  ldA4(aB, rdA0, 4, k0); ldB4(bQ, rdB0, k1);
  stage(pA0, lA0); stage(pA1, lA1);             // T1 (t=63) A halves
  mmq(aA, bP, 0);
  barrier_();
  ldA4(aA, rdA0, 0, k1);
  mmq(aB, bP, 4);
  barrier_();
  ldA4(aB, rdA0, 4, k1);
  mmq(aA, bQ, 0);
  VMW(0);
  barrier_();
  ldA4(aA, rdA1, 0, k0); ldB4(bP, rdB1, k0);
  mmq(aB, bQ, 4);
  barrier_();
  ldA4(aB, rdA1, 4, k0); ldB4(bQ, rdB1, k1);
  mmq(aA, bP, 0);
  barrier_();
  ldA4(aA, rdA1, 0, k1);
  mmq(aB, bP, 4);
  barrier_();
  ldA4(aB, rdA1, 4, k1);
  mmq(aA, bQ, 0);
  barrier_();
  mmq(aB, bQ, 4);

  // ---- epilogue: C/D layout col=lane&15, row=quad*4+reg; nontemporal ----
  const int cm = bm + wm * 128 + quad * 4;
  const int cn = bn + wn * 64 + l15;
#pragma unroll
  for (int g = 0; g < 4; ++g) {
    const int col = cn + g * 16;
    const float bv = bias[col];
#pragma unroll
    for (int m = 0; m < 8; ++m) {
      float* cp = C + (size_t)(cm + m * 16) * N_DIM + col;
      const f32x4 a = acc[m][g];
      __builtin_nontemporal_store(a[0] + bv, cp + 0 * N_DIM);
      __builtin_nontemporal_store(a[1] + bv, cp + 1 * N_DIM);
      __builtin_nontemporal_store(a[2] + bv, cp + 2 * N_DIM);
      __builtin_nontemporal_store(a[3] + bv, cp + 3 * N_DIM);
    }
  }
}

extern "C" void kernel_launch(void* const* d_in, const int* in_sizes, int n_in,
                              void* d_out, int out_size, void* d_ws, size_t ws_size,
                              hipStream_t stream) {
  const float* x = (const float*)d_in[0];
  const int* Wq = (const int*)d_in[1];
  const float* scale = (const float*)d_in[2];
  const float* zero = (const float*)d_in[3];
  const float* bias = (const float*)d_in[4];
  float* out = (float*)d_out;

  bf16* Xb = (bf16*)d_ws;                              // 8192*4096*2 = 64 MiB
  bf16* Wb = (bf16*)((char*)d_ws + (size_t)67108864);  // 11008*4096*2 = 86 MiB

  static int smem_set = 0;
  if (!smem_set) {
    (void)hipFuncSetAttribute((const void*)gemm_bt,
                              hipFuncAttributeMaxDynamicSharedMemorySize, 131072);
    smem_set = 1;
  }

  cvt_x<<<16384, 256, 0, stream>>>(x, Xb);                    // 8192*4096/8/256
  dequant_w<<<11008, 256, 0, stream>>>(Wq, scale, zero, Wb);  // 32*(NG/8)/256
  gemm_bt<<<1376, 512, 131072, stream>>>(Xb, Wb, bias, out);  // 32*43 blocks
}